// Round 1
// baseline (241.144 us; speedup 1.0000x reference)
//
#include <hip/hip_runtime.h>

#define H 128
#define W 128
#define HW 16384
#define C 64
#define NOC 64
#define NB 4

// ---------------------------------------------------------------------------
// Kernel 1: transpose x from NCHW (b,c,h,w) to NHWC (b,hw,c) for coalesced
// channel-contiguous bilinear gathers in the main kernel.
// grid: NB*256 blocks (64-pixel tiles), 256 threads.
// ---------------------------------------------------------------------------
__global__ __launch_bounds__(256) void transpose_x(const float* __restrict__ x,
                                                   float* __restrict__ xT) {
    __shared__ float T[64 * 64];  // swizzled [w][c]
    int blk = blockIdx.x;
    int b = blk >> 8;
    int hw0 = (blk & 255) << 6;
    int t = threadIdx.x;

    const float* xb = x + ((size_t)b * C) * HW + hw0;
    int cl = t >> 4;            // 0..15
    int wl = (t & 15) << 2;     // 0..60 step 4
#pragma unroll
    for (int rep = 0; rep < 4; ++rep) {
        int c = cl + (rep << 4);
        float4 v = *(const float4*)(xb + (size_t)c * HW + wl);
        float vv[4] = {v.x, v.y, v.z, v.w};
#pragma unroll
        for (int j = 0; j < 4; ++j) {
            int w = wl + j;
            int g = (w >> 2) & 7;
            T[w * 64 + (c ^ (g << 2))] = vv[j];
        }
    }
    __syncthreads();
    float* xTb = xT + ((size_t)b * HW + hw0) * C;
    int wr = t >> 4;
    int cr = (t & 15) << 2;
#pragma unroll
    for (int rep = 0; rep < 4; ++rep) {
        int w = wr + (rep << 4);
        int g = (w >> 2) & 7;
        float4 v = *(const float4*)(&T[w * 64 + (cr ^ (g << 2))]);
        *(float4*)(xTb + (size_t)w * C + cr) = v;
    }
}

// ---------------------------------------------------------------------------
// Kernel 2: 3x3x64->3 conv (offset head) + trig offset construction.
// Writes taps[b][k][pix] = (py, px) absolute sample coordinates.
// grid: (8,8,NB) blocks of (16,16).
// ---------------------------------------------------------------------------
__global__ __launch_bounds__(256) void offset_kernel(const float* __restrict__ x,
                                                     const float* __restrict__ ow,
                                                     const float* __restrict__ ob,
                                                     float2* __restrict__ taps) {
    __shared__ float ows[3 * 64 * 9];
    __shared__ float tile[18][19];
    int tx = threadIdx.x, ty = threadIdx.y;
    int t = ty * 16 + tx;
    for (int i = t; i < 1728; i += 256) ows[i] = ow[i];

    int b = blockIdx.z;
    int y0 = blockIdx.y * 16, x0 = blockIdx.x * 16;
    int gy = y0 + ty, gx = x0 + tx;
    float acc0 = ob[0], acc1 = ob[1], acc2 = ob[2];
    const float* xb = x + (size_t)b * C * HW;

    for (int c = 0; c < C; ++c) {
        __syncthreads();
        for (int i = t; i < 18 * 18; i += 256) {
            int iy = i / 18, ix = i - iy * 18;
            int yy = y0 - 1 + iy, xx = x0 - 1 + ix;
            float v = 0.f;
            if (yy >= 0 && yy < H && xx >= 0 && xx < W)
                v = xb[(size_t)c * HW + yy * W + xx];
            tile[iy][ix] = v;
        }
        __syncthreads();
        const float* owc = &ows[c * 9];  // ow[oc][c][kk], oc stride 576
#pragma unroll
        for (int dy = 0; dy < 3; ++dy)
#pragma unroll
            for (int dx = 0; dx < 3; ++dx) {
                float v = tile[ty + dy][tx + dx];
                int kk = dy * 3 + dx;
                acc0 += v * owc[kk];
                acc1 += v * owc[576 + kk];
                acc2 += v * owc[1152 + kk];
            }
    }

    // offsets: channels 0..8 = offy[t], 9..17 = offx[t]; tap k pairs
    // channels (2k, 2k+1) per the reference's reshape(B,K,2,Ho,Wo).
    float oyp1 = acc0 + 1.f, oxp1 = acc1 + 1.f;
    float sn = sinf(acc2), cs = cosf(acc2);
    float A = oxp1 * sn, Bc = oyp1 * cs, Cs = oyp1 * sn, D = oxp1 * cs;
    float offc[18];
    offc[0] = -A - Bc + 1.f;  offc[1] = -A;        offc[2] = -A + Bc - 1.f;
    offc[3] = -Bc + 1.f;      offc[4] = 0.f;       offc[5] = Bc - 1.f;
    offc[6] = A - Bc + 1.f;   offc[7] = A;         offc[8] = A + Bc - 1.f;
    offc[9] = -D + Cs + 1.f;  offc[10] = -D + 1.f; offc[11] = -D - Cs + 1.f;
    offc[12] = Cs;            offc[13] = 0.f;      offc[14] = -Cs;
    offc[15] = D + Cs - 1.f;  offc[16] = D - 1.f;  offc[17] = D - Cs - 1.f;

    int pix = gy * W + gx;
#pragma unroll
    for (int k = 0; k < 9; ++k) {
        float py = (float)(gy - 1 + k / 3) + offc[2 * k];
        float px = (float)(gx - 1 + k % 3) + offc[2 * k + 1];
        taps[((size_t)b * 9 + k) * HW + pix] = make_float2(py, px);
    }
}

// ---------------------------------------------------------------------------
// Kernel 3: weight reorder (oc,c,k) -> Wt[k][c][oc] for coalesced LDS staging.
// ---------------------------------------------------------------------------
__global__ __launch_bounds__(256) void reorder_w(const float* __restrict__ w,
                                                 float* __restrict__ wt) {
    int idx = blockIdx.x * 256 + threadIdx.x;
    if (idx >= NOC * C * 9) return;
    int oc = idx & 63;
    int rest = idx >> 6;
    int c = rest & 63;
    int k = rest >> 6;
    wt[idx] = w[((size_t)oc * C + c) * 9 + k];
}

// ---------------------------------------------------------------------------
// Kernel 4: fused bilinear-sample (im2col) + GEMM.
// Block: 256 threads = 128 pixels x 64 oc tile. 9 k-steps; per step stage
// S[64c][128p] (XOR-swizzled, 32KB) + W-slice (16KB) in LDS, then each
// thread contracts 8 pix x 4 oc over c=0..63.
// ---------------------------------------------------------------------------
__global__ __launch_bounds__(256, 2) void deform_gemm(const float* __restrict__ xT,
                                                      const float2* __restrict__ taps,
                                                      const float* __restrict__ wt,
                                                      float* __restrict__ out) {
    __shared__ float S[C * 128];   // swizzled [c][p]
    __shared__ float Wl[C * NOC];  // [c][oc]
    int t = threadIdx.x;
    int blk = blockIdx.x;
    int b = blk >> 7;
    int pix0 = (blk & 127) << 7;
    const float* xb = xT + (size_t)b * HW * C;
    const float2* tb = taps + (size_t)b * 9 * HW;

    float acc[8][4];
#pragma unroll
    for (int i = 0; i < 8; ++i)
#pragma unroll
        for (int j = 0; j < 4; ++j) acc[i][j] = 0.f;

    int c0 = (t & 15) << 2;   // sampling channel group
    int pg16 = t >> 4;        // sampling pixel sub-index
    int ocg = t & 15;         // contraction oc group (oc0 = ocg*4)
    int p0 = (t >> 4) << 3;   // contraction pixel base

#pragma unroll 1
    for (int k = 0; k < 9; ++k) {
        __syncthreads();  // protect S/Wl from previous iteration's readers
        // stage W[k] slice: 4096 floats
        {
            const float4* wsrc = (const float4*)(wt + k * 4096);
            float4* wdst = (float4*)Wl;
#pragma unroll
            for (int i = 0; i < 4; ++i) wdst[t + 256 * i] = wsrc[t + 256 * i];
        }
        // sampling: 8 iterations of 16 pixels, 16 threads/pixel (float4 of c)
#pragma unroll 2
        for (int it = 0; it < 8; ++it) {
            int p = it * 16 + pg16;
            float2 pp = tb[(size_t)k * HW + pix0 + p];
            float y0f = floorf(pp.x), x0f = floorf(pp.y);
            float fy = pp.x - y0f, fx = pp.y - x0f;
            int iy0 = (int)y0f, ix0 = (int)x0f;
            int iy1 = iy0 + 1, ix1 = ix0 + 1;
            bool vy0 = (iy0 >= 0) & (iy0 < H), vy1 = (iy1 >= 0) & (iy1 < H);
            bool vx0 = (ix0 >= 0) & (ix0 < W), vx1 = (ix1 >= 0) & (ix1 < W);
            float w00 = (vy0 & vx0) ? (1.f - fy) * (1.f - fx) : 0.f;
            float w01 = (vy0 & vx1) ? (1.f - fy) * fx : 0.f;
            float w10 = (vy1 & vx0) ? fy * (1.f - fx) : 0.f;
            float w11 = (vy1 & vx1) ? fy * fx : 0.f;
            int cy0 = min(max(iy0, 0), H - 1), cy1 = min(max(iy1, 0), H - 1);
            int cx0 = min(max(ix0, 0), W - 1), cx1 = min(max(ix1, 0), W - 1);
            const float* r00 = xb + ((cy0 * W + cx0) << 6) + c0;
            const float* r01 = xb + ((cy0 * W + cx1) << 6) + c0;
            const float* r10 = xb + ((cy1 * W + cx0) << 6) + c0;
            const float* r11 = xb + ((cy1 * W + cx1) << 6) + c0;
            float4 a00 = *(const float4*)r00;
            float4 a01 = *(const float4*)r01;
            float4 a10 = *(const float4*)r10;
            float4 a11 = *(const float4*)r11;
            float sv0 = w00 * a00.x + w01 * a01.x + w10 * a10.x + w11 * a11.x;
            float sv1 = w00 * a00.y + w01 * a01.y + w10 * a10.y + w11 * a11.y;
            float sv2 = w00 * a00.z + w01 * a01.z + w10 * a10.z + w11 * a11.z;
            float sv3 = w00 * a00.w + w01 * a01.w + w10 * a10.w + w11 * a11.w;
            float svv[4] = {sv0, sv1, sv2, sv3};
#pragma unroll
            for (int j = 0; j < 4; ++j) {
                int c = c0 + j;
                S[(c << 7) + (p ^ (((c >> 2) & 7) << 2))] = svv[j];
            }
        }
        __syncthreads();
        // contraction: acc[8 pix][4 oc] += S[c][p] * Wl[c][oc]
#pragma unroll 4
        for (int c = 0; c < C; ++c) {
            float4 wv = *(const float4*)(Wl + (c << 6) + (ocg << 2));
            int xk = ((c >> 2) & 7) << 2;
            const float* srow = S + (c << 7);
            float4 slo = *(const float4*)(srow + (p0 ^ xk));
            float4 shi = *(const float4*)(srow + ((p0 + 4) ^ xk));
            float sp[8] = {slo.x, slo.y, slo.z, slo.w, shi.x, shi.y, shi.z, shi.w};
#pragma unroll
            for (int ip = 0; ip < 8; ++ip) {
                acc[ip][0] += sp[ip] * wv.x;
                acc[ip][1] += sp[ip] * wv.y;
                acc[ip][2] += sp[ip] * wv.z;
                acc[ip][3] += sp[ip] * wv.w;
            }
        }
    }

    // epilogue: stage acc in LDS (reuse S) and write coalesced float4s
    __syncthreads();
#pragma unroll
    for (int ip = 0; ip < 8; ++ip) {
        int p = p0 + ip;
#pragma unroll
        for (int j = 0; j < 4; ++j) {
            int oc = (ocg << 2) + j;
            S[(oc << 7) + (p ^ (((oc >> 2) & 7) << 2))] = acc[ip][j];
        }
    }
    __syncthreads();
    float* ob_ = out + ((size_t)b * NOC) * HW + pix0;
#pragma unroll
    for (int rep = 0; rep < 2; ++rep) {
        int oc = (t >> 3) + (rep << 5);
        int xk = ((oc >> 2) & 7) << 2;
        int pxb = (t & 7) << 4;
        const float* srow = S + (oc << 7);
#pragma unroll
        for (int q = 0; q < 4; ++q) {
            int p = pxb + (q << 2);
            float4 v = *(const float4*)(srow + (p ^ xk));
            *(float4*)(ob_ + (size_t)oc * HW + p) = v;
        }
    }
}

// ---------------------------------------------------------------------------
// Launch. Workspace layout (needs ~20.7 MB):
//   [0, 16 MiB)          xT   (NHWC x, 4*16384*64 floats)
//   [16 MiB, +4.5 MB)    taps (4*9*16384 float2)
//   [20.5 MB, +144 KB)   wt   (reordered weight)
// ---------------------------------------------------------------------------
extern "C" void kernel_launch(void* const* d_in, const int* in_sizes, int n_in,
                              void* d_out, int out_size, void* d_ws, size_t ws_size,
                              hipStream_t stream) {
    const float* x = (const float*)d_in[0];
    const float* ow = (const float*)d_in[1];
    const float* ob = (const float*)d_in[2];
    const float* w = (const float*)d_in[3];
    float* out = (float*)d_out;

    char* ws = (char*)d_ws;
    float* xT = (float*)ws;                                  // 16,777,216 B
    float2* taps = (float2*)(ws + (size_t)16777216);         //  4,718,592 B
    float* wt = (float*)(ws + (size_t)16777216 + 4718592);   //    147,456 B

    hipLaunchKernelGGL(transpose_x, dim3(NB * 256), dim3(256), 0, stream, x, xT);
    hipLaunchKernelGGL(offset_kernel, dim3(8, 8, NB), dim3(16, 16), 0, stream,
                       x, ow, ob, taps);
    hipLaunchKernelGGL(reorder_w, dim3(144), dim3(256), 0, stream, w, wt);
    hipLaunchKernelGGL(deform_gemm, dim3(NB * 128), dim3(256), 0, stream,
                       xT, taps, wt, out);
}

// Round 8
// 187.791 us; speedup vs baseline: 1.2841x; 1.2841x over previous
//
#include <hip/hip_runtime.h>

#define H 128
#define W 128
#define HW 16384
#define C 64
#define NOC 64
#define NB 4

// ---------------------------------------------------------------------------
// Kernel 1: transpose x from NCHW (b,c,h,w) to NHWC (b,hw,c).
// ---------------------------------------------------------------------------
__global__ __launch_bounds__(256) void transpose_x(const float* __restrict__ x,
                                                   float* __restrict__ xT) {
    __shared__ float T[64 * 64];  // swizzled [w][c]
    int blk = blockIdx.x;
    int b = blk >> 8;
    int hw0 = (blk & 255) << 6;
    int t = threadIdx.x;

    const float* xb = x + ((size_t)b * C) * HW + hw0;
    int cl = t >> 4;            // 0..15
    int wl = (t & 15) << 2;     // 0..60 step 4
#pragma unroll
    for (int rep = 0; rep < 4; ++rep) {
        int c = cl + (rep << 4);
        float4 v = *(const float4*)(xb + (size_t)c * HW + wl);
        float vv[4] = {v.x, v.y, v.z, v.w};
#pragma unroll
        for (int j = 0; j < 4; ++j) {
            int w = wl + j;
            int g = (w >> 2) & 7;
            T[w * 64 + (c ^ (g << 2))] = vv[j];
        }
    }
    __syncthreads();
    float* xTb = xT + ((size_t)b * HW + hw0) * C;
    int wr = t >> 4;
    int cr = (t & 15) << 2;
#pragma unroll
    for (int rep = 0; rep < 4; ++rep) {
        int w = wr + (rep << 4);
        int g = (w >> 2) & 7;
        float4 v = *(const float4*)(&T[w * 64 + (cr ^ (g << 2))]);
        *(float4*)(xTb + (size_t)w * C + cr) = v;
    }
}

// ---------------------------------------------------------------------------
// Kernel 2 (v2): offset head 3x3 conv + trig tap construction, NHWC input.
// FLAT 256-thread block (launch dim3(256) — NOT dim3(16,16); kernel indexes
// t = threadIdx.x and derives tx/ty itself. R4 bug: 2-D launch left t<16).
// 16x16 pixel tile; channels in 4 chunks of 16 staged in LDS as [c][18*18].
// ---------------------------------------------------------------------------
__global__ __launch_bounds__(256) void offset_kernel(const float* __restrict__ xT,
                                                     const float* __restrict__ ow,
                                                     const float* __restrict__ ob,
                                                     float2* __restrict__ taps) {
    __shared__ float ows[3 * 64 * 9];    // ow[oc][c][kk], oc stride 576
    __shared__ float tile[16][18 * 18];
    int t = threadIdx.x;
    int tx = t & 15, ty = t >> 4;
    for (int i = t; i < 1728; i += 256) ows[i] = ow[i];

    int b = blockIdx.z;
    int y0 = blockIdx.y * 16, x0 = blockIdx.x * 16;
    int gy = y0 + ty, gx = x0 + tx;
    float acc0 = ob[0], acc1 = ob[1], acc2 = ob[2];
    const float* xb = xT + (size_t)b * HW * C;

#pragma unroll 1
    for (int cc = 0; cc < 4; ++cc) {
        int cbase = cc << 4;
        __syncthreads();
        // load 18x18 halo tile x 16 channels: 1296 float4s
        for (int i = t; i < 1296; i += 256) {
            int px = i >> 2, cq = i & 3;
            int iy = px / 18, ix = px - iy * 18;
            int yy = y0 - 1 + iy, xx = x0 - 1 + ix;
            float4 v = make_float4(0.f, 0.f, 0.f, 0.f);
            if (yy >= 0 && yy < H && xx >= 0 && xx < W)
                v = *(const float4*)(xb + (((size_t)(yy * W + xx)) << 6) + cbase + (cq << 2));
            tile[(cq << 2) + 0][px] = v.x;
            tile[(cq << 2) + 1][px] = v.y;
            tile[(cq << 2) + 2][px] = v.z;
            tile[(cq << 2) + 3][px] = v.w;
        }
        __syncthreads();
#pragma unroll 2
        for (int c = 0; c < 16; ++c) {
            const float* owc = &ows[(cbase + c) * 9];
            const float* trow = &tile[c][0];
#pragma unroll
            for (int dy = 0; dy < 3; ++dy)
#pragma unroll
                for (int dx = 0; dx < 3; ++dx) {
                    float v = trow[(ty + dy) * 18 + tx + dx];
                    int kk = dy * 3 + dx;
                    acc0 += v * owc[kk];
                    acc1 += v * owc[576 + kk];
                    acc2 += v * owc[1152 + kk];
                }
        }
    }

    float oyp1 = acc0 + 1.f, oxp1 = acc1 + 1.f;
    float sn = sinf(acc2), cs = cosf(acc2);
    float A = oxp1 * sn, Bc = oyp1 * cs, Cs = oyp1 * sn, D = oxp1 * cs;
    float offc[18];
    offc[0] = -A - Bc + 1.f;  offc[1] = -A;        offc[2] = -A + Bc - 1.f;
    offc[3] = -Bc + 1.f;      offc[4] = 0.f;       offc[5] = Bc - 1.f;
    offc[6] = A - Bc + 1.f;   offc[7] = A;         offc[8] = A + Bc - 1.f;
    offc[9] = -D + Cs + 1.f;  offc[10] = -D + 1.f; offc[11] = -D - Cs + 1.f;
    offc[12] = Cs;            offc[13] = 0.f;      offc[14] = -Cs;
    offc[15] = D + Cs - 1.f;  offc[16] = D - 1.f;  offc[17] = D - Cs - 1.f;

    int pix = gy * W + gx;
#pragma unroll
    for (int k = 0; k < 9; ++k) {
        float py = (float)(gy - 1 + k / 3) + offc[2 * k];
        float px = (float)(gx - 1 + k % 3) + offc[2 * k + 1];
        taps[((size_t)b * 9 + k) * HW + pix] = make_float2(py, px);
    }
}

// ---------------------------------------------------------------------------
// Kernel 3: weight reorder (oc,c,k) -> Wt[k][c][oc].
// ---------------------------------------------------------------------------
__global__ __launch_bounds__(256) void reorder_w(const float* __restrict__ w,
                                                 float* __restrict__ wt) {
    int idx = blockIdx.x * 256 + threadIdx.x;
    if (idx >= NOC * C * 9) return;
    int oc = idx & 63;
    int rest = idx >> 6;
    int c = rest & 63;
    int k = rest >> 6;
    wt[idx] = w[((size_t)oc * C + c) * 9 + k];
}

// ---------------------------------------------------------------------------
// Kernel 4 (v2): fused bilinear-sample + GEMM.
//  - XCD-bijective block swizzle: each XCD owns 64 contiguous rows
//    (~2.7 MB working set, fits its 4 MB L2).
//  - meta phase: bilinear weights + byte-offsets computed ONCE per
//    (pixel,k) by 128 threads, overlapped with the contract phase of the
//    previous k; sampling reads them via free LDS broadcast.
// ---------------------------------------------------------------------------
__global__ __launch_bounds__(256, 2) void deform_gemm(const float* __restrict__ xT,
                                                      const float2* __restrict__ taps,
                                                      const float* __restrict__ wt,
                                                      float* __restrict__ out) {
    __shared__ float S[C * 128];     // 32 KB, swizzled [c][p]
    __shared__ float Wl[C * NOC];    // 16 KB, [c][oc]
    __shared__ float metaF[128 * 4]; // 2 KB: w00,w01,w10,w11 per pixel
    __shared__ int   metaI[128 * 4]; // 2 KB: float-offsets of 4 corners
    int t = threadIdx.x;
    int orig = blockIdx.x;
    int blk = ((orig & 7) << 6) + (orig >> 3);  // XCD-contiguous, bijective (512%8==0)
    int b = blk >> 7;
    int pix0 = (blk & 127) << 7;
    const float* xb = xT + (size_t)b * HW * C;
    const float2* tb = taps + (size_t)b * 9 * HW;

    float acc[8][4];
#pragma unroll
    for (int i = 0; i < 8; ++i)
#pragma unroll
        for (int j = 0; j < 4; ++j) acc[i][j] = 0.f;

    int c0 = (t & 15) << 2;   // sampling channel group
    int pg16 = t >> 4;        // sampling pixel sub-index
    int ocg = t & 15;         // contraction oc group
    int p0 = (t >> 4) << 3;   // contraction pixel base

    auto compute_meta = [&](int k) {
        if (t < 128) {
            float2 pp = tb[(size_t)k * HW + pix0 + t];
            float y0f = floorf(pp.x), x0f = floorf(pp.y);
            float fy = pp.x - y0f, fx = pp.y - x0f;
            int iy0 = (int)y0f, ix0 = (int)x0f;
            int iy1 = iy0 + 1, ix1 = ix0 + 1;
            bool vy0 = (iy0 >= 0) & (iy0 < H), vy1 = (iy1 >= 0) & (iy1 < H);
            bool vx0 = (ix0 >= 0) & (ix0 < W), vx1 = (ix1 >= 0) & (ix1 < W);
            float w00 = (vy0 & vx0) ? (1.f - fy) * (1.f - fx) : 0.f;
            float w01 = (vy0 & vx1) ? (1.f - fy) * fx : 0.f;
            float w10 = (vy1 & vx0) ? fy * (1.f - fx) : 0.f;
            float w11 = (vy1 & vx1) ? fy * fx : 0.f;
            int cy0 = min(max(iy0, 0), H - 1), cy1 = min(max(iy1, 0), H - 1);
            int cx0 = min(max(ix0, 0), W - 1), cx1 = min(max(ix1, 0), W - 1);
            *(float4*)&metaF[t << 2] = make_float4(w00, w01, w10, w11);
            *(int4*)&metaI[t << 2] = make_int4((cy0 * W + cx0) << 6, (cy0 * W + cx1) << 6,
                                               (cy1 * W + cx0) << 6, (cy1 * W + cx1) << 6);
        }
    };

    compute_meta(0);

#pragma unroll 1
    for (int k = 0; k < 9; ++k) {
        __syncthreads();  // orders: prev contract reads < S/Wl writes; meta writes < meta reads
        // stage W[k] slice: 4096 floats
        {
            const float4* wsrc = (const float4*)(wt + k * 4096);
            float4* wdst = (float4*)Wl;
#pragma unroll
            for (int i = 0; i < 4; ++i) wdst[t + 256 * i] = wsrc[t + 256 * i];
        }
        // sampling: 8 iterations of 16 pixels, 16 threads/pixel
#pragma unroll 2
        for (int it = 0; it < 8; ++it) {
            int p = (it << 4) + pg16;
            float4 wv = *(const float4*)&metaF[p << 2];   // broadcast
            int4 ov = *(const int4*)&metaI[p << 2];       // broadcast
            float4 a00 = *(const float4*)(xb + ov.x + c0);
            float4 a01 = *(const float4*)(xb + ov.y + c0);
            float4 a10 = *(const float4*)(xb + ov.z + c0);
            float4 a11 = *(const float4*)(xb + ov.w + c0);
            float sv0 = wv.x * a00.x + wv.y * a01.x + wv.z * a10.x + wv.w * a11.x;
            float sv1 = wv.x * a00.y + wv.y * a01.y + wv.z * a10.y + wv.w * a11.y;
            float sv2 = wv.x * a00.z + wv.y * a01.z + wv.z * a10.z + wv.w * a11.z;
            float sv3 = wv.x * a00.w + wv.y * a01.w + wv.z * a10.w + wv.w * a11.w;
            float svv[4] = {sv0, sv1, sv2, sv3};
#pragma unroll
            for (int j = 0; j < 4; ++j) {
                int c = c0 + j;
                S[(c << 7) + (p ^ (((c >> 2) & 7) << 2))] = svv[j];
            }
        }
        __syncthreads();
        // contraction: acc[8 pix][4 oc] += S[c][p] * Wl[c][oc]
#pragma unroll 4
        for (int c = 0; c < C; ++c) {
            float4 wv = *(const float4*)(Wl + (c << 6) + (ocg << 2));
            int xk = ((c >> 2) & 7) << 2;
            const float* srow = S + (c << 7);
            float4 slo = *(const float4*)(srow + (p0 ^ xk));
            float4 shi = *(const float4*)(srow + ((p0 + 4) ^ xk));
            float sp[8] = {slo.x, slo.y, slo.z, slo.w, shi.x, shi.y, shi.z, shi.w};
#pragma unroll
            for (int ip = 0; ip < 8; ++ip) {
                acc[ip][0] += sp[ip] * wv.x;
                acc[ip][1] += sp[ip] * wv.y;
                acc[ip][2] += sp[ip] * wv.z;
                acc[ip][3] += sp[ip] * wv.w;
            }
        }
        // overlap next k's tap loads + weight math under this phase
        if (k < 8) compute_meta(k + 1);
    }

    // epilogue: stage acc in LDS (reuse S) and write coalesced float4s
    __syncthreads();
#pragma unroll
    for (int ip = 0; ip < 8; ++ip) {
        int p = p0 + ip;
#pragma unroll
        for (int j = 0; j < 4; ++j) {
            int oc = (ocg << 2) + j;
            S[(oc << 7) + (p ^ (((oc >> 2) & 7) << 2))] = acc[ip][j];
        }
    }
    __syncthreads();
    float* ob_ = out + ((size_t)b * NOC) * HW + pix0;
#pragma unroll
    for (int rep = 0; rep < 2; ++rep) {
        int oc = (t >> 3) + (rep << 5);
        int xk = ((oc >> 2) & 7) << 2;
        int pxb = (t & 7) << 4;
        const float* srow = S + (oc << 7);
#pragma unroll
        for (int q = 0; q < 4; ++q) {
            int p = pxb + (q << 2);
            float4 v = *(const float4*)(srow + (p ^ xk));
            *(float4*)(ob_ + (size_t)oc * HW + p) = v;
        }
    }
}

// ---------------------------------------------------------------------------
// Launch. Workspace layout (~20.7 MB used):
//   [0, 16 MiB)          xT   (NHWC x)
//   [16 MiB, +4.5 MB)    taps (4*9*16384 float2)
//   [+, +144 KB)         wt   (reordered weight)
// ---------------------------------------------------------------------------
extern "C" void kernel_launch(void* const* d_in, const int* in_sizes, int n_in,
                              void* d_out, int out_size, void* d_ws, size_t ws_size,
                              hipStream_t stream) {
    const float* x = (const float*)d_in[0];
    const float* ow = (const float*)d_in[1];
    const float* ob = (const float*)d_in[2];
    const float* w = (const float*)d_in[3];
    float* out = (float*)d_out;

    char* ws = (char*)d_ws;
    float* xT = (float*)ws;                                  // 16,777,216 B
    float2* taps = (float2*)(ws + (size_t)16777216);         //  4,718,592 B
    float* wt = (float*)(ws + (size_t)16777216 + 4718592);   //    147,456 B

    hipLaunchKernelGGL(transpose_x, dim3(NB * 256), dim3(256), 0, stream, x, xT);
    hipLaunchKernelGGL(reorder_w, dim3(144), dim3(256), 0, stream, w, wt);
    // NOTE: flat 256-thread block — offset_kernel derives tx/ty from
    // threadIdx.x. (R4 failure: dim3(16,16) here left threadIdx.x<16.)
    hipLaunchKernelGGL(offset_kernel, dim3(8, 8, NB), dim3(256), 0, stream,
                       xT, ow, ob, taps);
    hipLaunchKernelGGL(deform_gemm, dim3(NB * 128), dim3(256), 0, stream,
                       xT, taps, wt, out);
}

// Round 15
// 178.179 us; speedup vs baseline: 1.3534x; 1.0539x over previous
//
#include <hip/hip_runtime.h>

#define H 128
#define W 128
#define HW 16384
#define C 64
#define NOC 64
#define NB 4

// ---------------------------------------------------------------------------
// Kernel 1: transpose x from NCHW (b,c,h,w) to NHWC (b,hw,c).  [R1/R8-validated]
// ---------------------------------------------------------------------------
__global__ __launch_bounds__(256) void transpose_x(const float* __restrict__ x,
                                                   float* __restrict__ xT) {
    __shared__ float T[64 * 64];  // swizzled [w][c]
    int blk = blockIdx.x;
    int b = blk >> 8;
    int hw0 = (blk & 255) << 6;
    int t = threadIdx.x;

    const float* xb = x + ((size_t)b * C) * HW + hw0;
    int cl = t >> 4;            // 0..15
    int wl = (t & 15) << 2;     // 0..60 step 4
#pragma unroll
    for (int rep = 0; rep < 4; ++rep) {
        int c = cl + (rep << 4);
        float4 v = *(const float4*)(xb + (size_t)c * HW + wl);
        float vv[4] = {v.x, v.y, v.z, v.w};
#pragma unroll
        for (int j = 0; j < 4; ++j) {
            int w = wl + j;
            int g = (w >> 2) & 7;
            T[w * 64 + (c ^ (g << 2))] = vv[j];
        }
    }
    __syncthreads();
    float* xTb = xT + ((size_t)b * HW + hw0) * C;
    int wr = t >> 4;
    int cr = (t & 15) << 2;
#pragma unroll
    for (int rep = 0; rep < 4; ++rep) {
        int w = wr + (rep << 4);
        int g = (w >> 2) & 7;
        float4 v = *(const float4*)(&T[w * 64 + (cr ^ (g << 2))]);
        *(float4*)(xTb + (size_t)w * C + cr) = v;
    }
}

// ---------------------------------------------------------------------------
// Kernel 2 (v3b): offset head 3x3 conv + tap construction — per-pixel-group.
// KEPT as the bisect's experimental variable (R12/R13/R14).
//
// CHANNEL-PAIRING WARNING (R9 bug): the reference reshapes the 18-channel
// concat [offy(9); offx(9)] as (K,2) — tap k's y-offset is channel 2k and
// its x-offset is channel 2k+1, STRADDLING the offy/offx tables. chval(m)
// implements the straddled mapping; do NOT "fix" it to (offy[k], offx[k]).
//   m<9 : offy[m] = (jy-1)A + (jx-1)(Bc-1),  j=m
//   m>=9: offx[j] = (jy-1)(D-1) - (jx-1)Cs,  j=m-9   (verified vs R8 table)
// ---------------------------------------------------------------------------
__global__ __launch_bounds__(256) void offset_kernel(const float* __restrict__ xT,
                                                     const float* __restrict__ ow,
                                                     const float* __restrict__ ob,
                                                     float2* __restrict__ taps) {
    __shared__ float ows[1728];   // ow[oc][c][kk]: oc*576 + c*9 + kk
    int t = threadIdx.x;
    for (int i = t; i < 1728; i += 256) ows[i] = ow[i];
    float b0 = ob[0], b1 = ob[1], b2 = ob[2];
    __syncthreads();

    int gid = blockIdx.x * 256 + t;
    int gp = gid >> 4;               // global pixel: b*HW + pix
    int cg = t & 15;                 // channel group (4 ch)
    int b = gp >> 14;
    int pix = gp & 16383;
    int gy = pix >> 7, gx = pix & 127;

    const float* xb = xT + (((size_t)b) << 14) * C;
    float acc0 = 0.f, acc1 = 0.f, acc2 = 0.f;
#pragma unroll
    for (int k = 0; k < 9; ++k) {
        const int dy = k / 3 - 1, dx = k % 3 - 1;
        int yy = gy + dy, xx = gx + dx;
        bool valid = (yy >= 0) & (yy < H) & (xx >= 0) & (xx < W);
        int cy = min(max(yy, 0), H - 1), cx = min(max(xx, 0), W - 1);
        float4 v = *(const float4*)(xb + (((size_t)(cy * W + cx)) << 6) + (cg << 2));
        float m = valid ? 1.f : 0.f;
        float vj[4] = {v.x * m, v.y * m, v.z * m, v.w * m};
        const float* wp = &ows[(cg << 2) * 9 + k];
#pragma unroll
        for (int j = 0; j < 4; ++j) {
            acc0 += vj[j] * wp[j * 9];
            acc1 += vj[j] * wp[576 + j * 9];
            acc2 += vj[j] * wp[1152 + j * 9];
        }
    }
    // butterfly reduce within the 16-lane pixel group
#pragma unroll
    for (int s = 1; s < 16; s <<= 1) {
        acc0 += __shfl_xor(acc0, s);
        acc1 += __shfl_xor(acc1, s);
        acc2 += __shfl_xor(acc2, s);
    }
    acc0 += b0; acc1 += b1; acc2 += b2;

    if (cg < 9) {
        float oyp1 = acc0 + 1.f, oxp1 = acc1 + 1.f;
        float sn = sinf(acc2), cs = cosf(acc2);
        float A = oxp1 * sn, Bc = oyp1 * cs, Cs = oyp1 * sn, D = oxp1 * cs;
        // straddled channel value (see header comment)
        auto chval = [&](int m) {
            int j = (m < 9) ? m : m - 9;
            float jy = (float)(j / 3 - 1), jx = (float)(j % 3 - 1);
            return (m < 9) ? (jy * A + jx * (Bc - 1.f))
                           : (jy * (D - 1.f) - jx * Cs);
        };
        int ky = (cg >= 6) ? 2 : ((cg >= 3) ? 1 : 0);
        int kx = cg - ky * 3;
        float py = (float)(gy + ky - 1) + chval(2 * cg);
        float px = (float)(gx + kx - 1) + chval(2 * cg + 1);
        taps[(((size_t)b * 9 + cg) << 14) + pix] = make_float2(py, px);
    }
}

// ---------------------------------------------------------------------------
// Kernel 3: weight reorder (oc,c,k) -> Wt[k][c][oc].  [R1/R8-validated]
// ---------------------------------------------------------------------------
__global__ __launch_bounds__(256) void reorder_w(const float* __restrict__ w,
                                                 float* __restrict__ wt) {
    int idx = blockIdx.x * 256 + threadIdx.x;
    if (idx >= NOC * C * 9) return;
    int oc = idx & 63;
    int rest = idx >> 6;
    int c = rest & 63;
    int k = rest >> 6;
    wt[idx] = w[((size_t)oc * C + c) * 9 + k];
}

// ---------------------------------------------------------------------------
// Kernel 4: fused bilinear-sample + GEMM — REVERTED to the R8-validated v2
// (Wl LDS staging, launch_bounds(256,2), 52KB LDS) as the bisect control.
// The R9 "v3" (W-from-global, 4 blocks/CU) is under suspicion for the
// nondeterministic R10/R11 failures; do not re-land it without a clean
// A/B against this variant.
// ---------------------------------------------------------------------------
__global__ __launch_bounds__(256, 2) void deform_gemm(const float* __restrict__ xT,
                                                      const float2* __restrict__ taps,
                                                      const float* __restrict__ wt,
                                                      float* __restrict__ out) {
    __shared__ float S[C * 128];     // 32 KB, swizzled [c][p]
    __shared__ float Wl[C * NOC];    // 16 KB, [c][oc]
    __shared__ float metaF[128 * 4]; // 2 KB: w00,w01,w10,w11 per pixel
    __shared__ int   metaI[128 * 4]; // 2 KB: float-offsets of 4 corners
    int t = threadIdx.x;
    int orig = blockIdx.x;
    int blk = ((orig & 7) << 6) + (orig >> 3);  // XCD-contiguous, bijective (512%8==0)
    int b = blk >> 7;
    int pix0 = (blk & 127) << 7;
    const float* xb = xT + (size_t)b * HW * C;
    const float2* tb = taps + (size_t)b * 9 * HW;

    float acc[8][4];
#pragma unroll
    for (int i = 0; i < 8; ++i)
#pragma unroll
        for (int j = 0; j < 4; ++j) acc[i][j] = 0.f;

    int c0 = (t & 15) << 2;   // sampling channel group
    int pg16 = t >> 4;        // sampling pixel sub-index
    int ocg = t & 15;         // contraction oc group
    int p0 = (t >> 4) << 3;   // contraction pixel base

    auto compute_meta = [&](int k) {
        if (t < 128) {
            float2 pp = tb[(size_t)k * HW + pix0 + t];
            float y0f = floorf(pp.x), x0f = floorf(pp.y);
            float fy = pp.x - y0f, fx = pp.y - x0f;
            int iy0 = (int)y0f, ix0 = (int)x0f;
            int iy1 = iy0 + 1, ix1 = ix0 + 1;
            bool vy0 = (iy0 >= 0) & (iy0 < H), vy1 = (iy1 >= 0) & (iy1 < H);
            bool vx0 = (ix0 >= 0) & (ix0 < W), vx1 = (ix1 >= 0) & (ix1 < W);
            float w00 = (vy0 & vx0) ? (1.f - fy) * (1.f - fx) : 0.f;
            float w01 = (vy0 & vx1) ? (1.f - fy) * fx : 0.f;
            float w10 = (vy1 & vx0) ? fy * (1.f - fx) : 0.f;
            float w11 = (vy1 & vx1) ? fy * fx : 0.f;
            int cy0 = min(max(iy0, 0), H - 1), cy1 = min(max(iy1, 0), H - 1);
            int cx0 = min(max(ix0, 0), W - 1), cx1 = min(max(ix1, 0), W - 1);
            *(float4*)&metaF[t << 2] = make_float4(w00, w01, w10, w11);
            *(int4*)&metaI[t << 2] = make_int4((cy0 * W + cx0) << 6, (cy0 * W + cx1) << 6,
                                               (cy1 * W + cx0) << 6, (cy1 * W + cx1) << 6);
        }
    };

    compute_meta(0);

#pragma unroll 1
    for (int k = 0; k < 9; ++k) {
        __syncthreads();  // orders: prev contract reads < S/Wl writes; meta writes < meta reads
        // stage W[k] slice: 4096 floats
        {
            const float4* wsrc = (const float4*)(wt + k * 4096);
            float4* wdst = (float4*)Wl;
#pragma unroll
            for (int i = 0; i < 4; ++i) wdst[t + 256 * i] = wsrc[t + 256 * i];
        }
        // sampling: 8 iterations of 16 pixels, 16 threads/pixel
#pragma unroll 2
        for (int it = 0; it < 8; ++it) {
            int p = (it << 4) + pg16;
            float4 wv = *(const float4*)&metaF[p << 2];   // broadcast
            int4 ov = *(const int4*)&metaI[p << 2];       // broadcast
            float4 a00 = *(const float4*)(xb + ov.x + c0);
            float4 a01 = *(const float4*)(xb + ov.y + c0);
            float4 a10 = *(const float4*)(xb + ov.z + c0);
            float4 a11 = *(const float4*)(xb + ov.w + c0);
            float sv0 = wv.x * a00.x + wv.y * a01.x + wv.z * a10.x + wv.w * a11.x;
            float sv1 = wv.x * a00.y + wv.y * a01.y + wv.z * a10.y + wv.w * a11.y;
            float sv2 = wv.x * a00.z + wv.y * a01.z + wv.z * a10.z + wv.w * a11.z;
            float sv3 = wv.x * a00.w + wv.y * a01.w + wv.z * a10.w + wv.w * a11.w;
            float svv[4] = {sv0, sv1, sv2, sv3};
#pragma unroll
            for (int j = 0; j < 4; ++j) {
                int c = c0 + j;
                S[(c << 7) + (p ^ (((c >> 2) & 7) << 2))] = svv[j];
            }
        }
        __syncthreads();
        // contraction: acc[8 pix][4 oc] += S[c][p] * Wl[c][oc]
#pragma unroll 4
        for (int c = 0; c < C; ++c) {
            float4 wv = *(const float4*)(Wl + (c << 6) + (ocg << 2));
            int xk = ((c >> 2) & 7) << 2;
            const float* srow = S + (c << 7);
            float4 slo = *(const float4*)(srow + (p0 ^ xk));
            float4 shi = *(const float4*)(srow + ((p0 + 4) ^ xk));
            float sp[8] = {slo.x, slo.y, slo.z, slo.w, shi.x, shi.y, shi.z, shi.w};
#pragma unroll
            for (int ip = 0; ip < 8; ++ip) {
                acc[ip][0] += sp[ip] * wv.x;
                acc[ip][1] += sp[ip] * wv.y;
                acc[ip][2] += sp[ip] * wv.z;
                acc[ip][3] += sp[ip] * wv.w;
            }
        }
        // overlap next k's tap loads + weight math under this phase
        if (k < 8) compute_meta(k + 1);
    }

    // epilogue: stage acc in LDS (reuse S) and write coalesced float4s
    __syncthreads();
#pragma unroll
    for (int ip = 0; ip < 8; ++ip) {
        int p = p0 + ip;
#pragma unroll
        for (int j = 0; j < 4; ++j) {
            int oc = (ocg << 2) + j;
            S[(oc << 7) + (p ^ (((oc >> 2) & 7) << 2))] = acc[ip][j];
        }
    }
    __syncthreads();
    float* ob_ = out + ((size_t)b * NOC) * HW + pix0;
#pragma unroll
    for (int rep = 0; rep < 2; ++rep) {
        int oc = (t >> 3) + (rep << 5);
        int xk = ((oc >> 2) & 7) << 2;
        int pxb = (t & 7) << 4;
        const float* srow = S + (oc << 7);
#pragma unroll
        for (int q = 0; q < 4; ++q) {
            int p = pxb + (q << 2);
            float4 v = *(const float4*)(srow + (p ^ xk));
            *(float4*)(ob_ + (size_t)oc * HW + p) = v;
        }
    }
}

// ---------------------------------------------------------------------------
// Launch. Workspace layout (~21.6 MB used):
//   [0, 16 MiB)          xT   (NHWC x)
//   [16 MiB, +4.5 MB)    taps (4*9*16384 float2)
//   [+, +144 KB)         wt   (reordered weight)
// ---------------------------------------------------------------------------
extern "C" void kernel_launch(void* const* d_in, const int* in_sizes, int n_in,
                              void* d_out, int out_size, void* d_ws, size_t ws_size,
                              hipStream_t stream) {
    const float* x = (const float*)d_in[0];
    const float* ow = (const float*)d_in[1];
    const float* ob = (const float*)d_in[2];
    const float* w = (const float*)d_in[3];
    float* out = (float*)d_out;

    char* ws = (char*)d_ws;
    float* xT = (float*)ws;                                  // 16,777,216 B
    float2* taps = (float2*)(ws + (size_t)16777216);         //  4,718,592 B
    float* wt = (float*)(ws + (size_t)16777216 + 4718592);   //    147,456 B

    hipLaunchKernelGGL(transpose_x, dim3(NB * 256), dim3(256), 0, stream, x, xT);
    hipLaunchKernelGGL(reorder_w, dim3(144), dim3(256), 0, stream, w, wt);
    hipLaunchKernelGGL(offset_kernel, dim3(4096), dim3(256), 0, stream,
                       xT, ow, ob, taps);
    hipLaunchKernelGGL(deform_gemm, dim3(NB * 128), dim3(256), 0, stream,
                       xT, taps, wt, out);
}